// Round 18
// baseline (145.650 us; speedup 1.0000x reference)
//
#include <hip/hip_runtime.h>

// Bilinear backward warp, NCHW f32 — pipelined LDS channel loop, CGB=3.
// Block = 64x32 tile, 1024 threads. LDS: 2 ping-pong buffers x 3 planes of
// (72x40) RAD=4 halo'd tile (69 KB; 2 blocks/CU, thread-capped — same as
// R12's LDS size). Phase count 32/CGB: 16 -> 11. Measured phase overhead
// O ~ 7000cy is per-PHASE (R12: depth-2 null; R13-15: restructuring null),
// so fewer, fatter phases: T = 2 gen x 11 x (O + 1.5*W) ~ 98 us predicted.
// Per phase: issue next-phase DMA (3 slots/thread, lane-consecutive offsets
// {0,568,1136} — R10 wave-uniform-base rule; all 2160 slots covered,
// duplicates benign), gather current 3 planes, s_waitcnt vmcnt(6) + raw
// s_barrier (6 stores/thread stay in flight; 3 oldest = DMAs retired).

#define TSX 64
#define TSY 32
#define RAD 4
#define LW  (TSX + 2*RAD)     // 72
#define LH  (TSY + 2*RAD)     // 40
#define GPR (LW/4)            // 18 float4 groups per row
#define PLANE (LW*LH)         // 2880 floats = 11520 B
#define NV  (LH*GPR)          // 720 groups per plane
#define CGB 3                 // channels per buffer
#define NSTG (CGB*NV)         // 2160 DMA slots per phase
#define NTHREADS 1024
#define SOFF ((NSTG - NTHREADS) / 2)   // 568: slot stride (s=0,1,2)

static_assert(NSTG <= 3*NTHREADS, "3 slots per thread suffice");
static_assert(2*SOFF + NTHREADS == NSTG, "slot coverage exact");

#define GLOAD_LDS16(g, l)                                                  \
    __builtin_amdgcn_global_load_lds(                                      \
        (const __attribute__((address_space(1))) void*)(g),                \
        (__attribute__((address_space(3))) void*)(l), 16, 0, 0)

__global__ __launch_bounds__(NTHREADS, 8) void warp_pipe5(
    const float* __restrict__ img,
    const float* __restrict__ flow,
    const int* __restrict__ Hp,
    const int* __restrict__ Wp,
    float* __restrict__ out,
    int HW, int C)
{
    __shared__ __align__(16) float lds[2 * CGB * PLANE];   // 69120 B

    const int W = *Wp;
    const int H = *Hp;
    const int tilesX = (W + TSX - 1) / TSX;
    const int tilesY = (H + TSY - 1) / TSY;
    const int ntiles = tilesX * tilesY;
    const int bid = blockIdx.x;
    if (bid >= ntiles) return;

    // bijective XCD band swizzle
    const int q = ntiles >> 3, r = ntiles & 7;
    const int xcd = bid & 7, sub = bid >> 3;
    const int t = (xcd < r ? xcd*(q+1) : r*(q+1) + (xcd-r)*q) + sub;

    const int tileY = t / tilesX;
    const int tileX = t - tileY * tilesX;
    const int gx0 = tileX * TSX - RAD;   // always ≡ 0 (mod 4)
    const int gy0 = tileY * TSY - RAD;

    const int tid = threadIdx.x;
    const int lx  = tid & 63;
    const int rw  = (tid >> 6) * 2;      // 2 rows per thread
    const int gx  = tileX * TSX + lx;

    const float Wm1 = (float)(W - 1);
    const float Hm1 = (float)(H - 1);

    // ---- per-pixel precompute (once per tile) ----
    float wtl[2], wth[2], wbl[2], wbh[2];
    int enc[2], pixk[2] = {0, 0};
    #pragma unroll
    for (int k = 0; k < 2; ++k) {
        const int gy = tileY * TSY + rw + k;
        enc[k] = -2;
        if (gx >= W || gy >= H) continue;
        const int pix = gy * W + gx;
        pixk[k] = pix;
        const float u = flow[pix];
        const float v = flow[HW + pix];

        // normalize/denormalize round-trip omitted (identity, +-1 ulp)
        const float x = (float)gx + u;
        const float y = (float)gy + v;
        const float x0 = floorf(x), x1 = x0 + 1.0f;
        const float y0 = floorf(y), y1 = y0 + 1.0f;

        const int x0c = (int)fminf(fmaxf(x0, 0.0f), Wm1);
        const int x1c = (int)fminf(fmaxf(x1, 0.0f), Wm1);
        const int y0c = (int)fminf(fmaxf(y0, 0.0f), Hm1);
        const int y1c = (int)fminf(fmaxf(y1, 0.0f), Hm1);

        const float wa = (x1 - x) * (y1 - y);
        const float wb = (x1 - x) * (y - y0);
        const float wc = (x - x0) * (y1 - y);
        const float wd = (x - x0) * (y - y0);

        const int pbx = min(x0c, W - 2);
        const int pby = min(y0c, H - 2);

        const float wlt = (x0c == pbx ? wa : 0.f) + (x1c == pbx ? wc : 0.f);
        const float wht = (x0c != pbx ? wa : 0.f) + (x1c != pbx ? wc : 0.f);
        const float wlb = (x0c == pbx ? wb : 0.f) + (x1c == pbx ? wd : 0.f);
        const float whb = (x0c != pbx ? wb : 0.f) + (x1c != pbx ? wd : 0.f);
        const bool t0 = (y0c == pby), t1 = (y1c == pby);
        wtl[k] = (t0 ? wlt : 0.f) + (t1 ? wlb : 0.f);
        wth[k] = (t0 ? wht : 0.f) + (t1 ? whb : 0.f);
        wbl[k] = (t0 ? 0.f : wlt) + (t1 ? 0.f : wlb);
        wbh[k] = (t0 ? 0.f : wht) + (t1 ? 0.f : whb);

        const int lxp = pbx - gx0;
        const int lyb = pby - gy0;
        enc[k] = (lxp >= 0 && lxp <= LW-2 && lyb >= 0 && lyb <= LH-2)
               ? (lyb * LW + lxp) : -1;
    }

    float* optr0 = out + pixk[0];
    float* optr1 = out + pixk[1];

    // ---- staging descriptors (3 slots/thread, lane-consecutive) ----
    int spix[3], chrel[3], dst4[3];
    #pragma unroll
    for (int s = 0; s < 3; ++s) {
        const int idx = tid + s * SOFF;   // 0..1023, 568..1591, 1136..2159
        const int ch  = idx / NV;
        const int rem = idx - ch * NV;
        const int rr  = rem / GPR;
        const int g   = rem - rr * GPR;
        const int yy  = min(max(gy0 + rr, 0), H - 1);
        const int xs  = min(max(gx0 + 4*g, 0), W - 4);  // group fully in/out
        chrel[s] = ch;
        spix[s]  = yy * W + xs;
        dst4[s]  = idx * 4;
    }

    const int nph = (C + CGB - 1) / CGB;
    const bool fast = ((W & 3) == 0) && ((tileX+1)*TSX <= W)
                   && ((tileY+1)*TSY <= H);

    // gather one phase (up to 3 channels) from `cur`
    auto gather3 = [&](const float* cur, int c0) {
        #pragma unroll
        for (int k = 0; k < 2; ++k) {
            const int e = enc[k];
            if (e == -2) continue;
            float* o = (k == 0) ? optr0 : optr1;
            if (__builtin_expect(e >= 0, 1)) {
                const float* b0 = cur + e;
                const float a0 = wtl[k], a1 = wth[k];
                const float a2 = wbl[k], a3 = wbh[k];
                #pragma unroll
                for (int c = 0; c < CGB; ++c) {
                    if (c0 + c >= C) break;
                    const float* bc = b0 + c * PLANE;
                    o[(size_t)c * HW] = a0*bc[0] + a1*bc[1]
                                      + a2*bc[LW] + a3*bc[LW+1];
                }
            } else {
                // rare out-of-halo flow: recompute + global gather
                const int pix = pixk[k];
                const int gy  = tileY * TSY + rw + k;
                const float u = flow[pix];
                const float v = flow[HW + pix];
                const float x = (float)gx + u;
                const float y = (float)gy + v;
                const float x0 = floorf(x), y0f = floorf(y);
                const int x0c = (int)fminf(fmaxf(x0, 0.f), Wm1);
                const int x1c = (int)fminf(fmaxf(x0 + 1.f, 0.f), Wm1);
                const int y0c = (int)fminf(fmaxf(y0f, 0.f), Hm1);
                const int y1c = (int)fminf(fmaxf(y0f + 1.f, 0.f), Hm1);
                const float wa = (x0 + 1.f - x) * (y0f + 1.f - y);
                const float wb = (x0 + 1.f - x) * (y - y0f);
                const float wc = (x - x0) * (y0f + 1.f - y);
                const float wd = (x - x0) * (y - y0f);
                for (int c = 0; c < CGB && c0 + c < C; ++c) {
                    const float* ic = img + (size_t)(c0 + c) * HW;
                    o[(size_t)c * HW] =
                          wa * ic[(size_t)y0c*W + x0c] + wb * ic[(size_t)y1c*W + x0c]
                        + wc * ic[(size_t)y0c*W + x1c] + wd * ic[(size_t)y1c*W + x1c];
                }
            }
        }
    };

    if (fast) {
        // prologue: stage phase 0 into buffer A
        #pragma unroll
        for (int s = 0; s < 3; ++s) {
            const int chc = min(chrel[s], C - 1);
            GLOAD_LDS16(img + (size_t)chc * HW + spix[s], &lds[dst4[s]]);
        }
        asm volatile("s_waitcnt vmcnt(0)" ::: "memory");
        __builtin_amdgcn_s_barrier();
        __builtin_amdgcn_sched_barrier(0);

        float* cur = &lds[0];
        float* nxt = &lds[CGB * PLANE];

        for (int p = 0; p < nph; ++p) {
            const int c0 = p * CGB;

            if (p + 1 < nph) {   // issue DMA for next phase FIRST
                const int c0n = c0 + CGB;
                #pragma unroll
                for (int s = 0; s < 3; ++s) {
                    const int chc = min(c0n + chrel[s], C - 1);
                    GLOAD_LDS16(img + (size_t)chc * HW + spix[s], nxt + dst4[s]);
                }
            }
            __builtin_amdgcn_sched_barrier(0);   // pin: DMAs before stores

            gather3(cur, c0);                    // 6 stores per thread

            __builtin_amdgcn_sched_barrier(0);   // pin: stores before wait

            if (p + 1 < nph) {
                // in-order vmcnt: outstanding after D(p+1)x3 = S(p)x6 ->
                // vmcnt(6) retires the 3 oldest (our DMAs); the 6 output
                // stores stay in flight across the barrier. Non-tail phases
                // store exactly 6/thread (full tile, C%CGB tail is last).
                asm volatile("s_waitcnt vmcnt(6)" ::: "memory");
                __builtin_amdgcn_sched_barrier(0);
                __builtin_amdgcn_s_barrier();
                __builtin_amdgcn_sched_barrier(0);
            }
            float* tmp = cur; cur = nxt; nxt = tmp;
            optr0 += (size_t)CGB * HW;
            optr1 += (size_t)CGB * HW;
        }
    } else {
        // generic slow path (partial tiles / W%4!=0): scalar stage + full syncs
        for (int p = 0; p < nph; ++p) {
            const int c0 = p * CGB;
            __syncthreads();
            for (int i = tid; i < CGB * PLANE; i += NTHREADS) {
                const int ch  = i / PLANE;
                const int rem = i - ch * PLANE;
                const int rr  = rem / LW;
                const int cc  = rem - rr * LW;
                const int yy  = min(max(gy0 + rr, 0), H - 1);
                const int xx  = min(max(gx0 + cc, 0), W - 1);
                const int chc = min(c0 + ch, C - 1);
                lds[i] = img[(size_t)chc * HW + (size_t)yy * W + xx];
            }
            __syncthreads();
            gather3(&lds[0], c0);
            optr0 += (size_t)CGB * HW;
            optr1 += (size_t)CGB * HW;
        }
    }
}

extern "C" void kernel_launch(void* const* d_in, const int* in_sizes, int n_in,
                              void* d_out, int out_size, void* d_ws, size_t ws_size,
                              hipStream_t stream) {
    const float* img  = (const float*)d_in[0];
    const float* flow = (const float*)d_in[1];
    const int*   Hp   = (const int*)d_in[2];
    const int*   Wp   = (const int*)d_in[3];
    float* out = (float*)d_out;

    const int HW = in_sizes[1] / 2;    // flow is (1,2,H,W)
    const int C  = in_sizes[0] / HW;   // img is (1,C,H,W)

    // host doesn't know W,H (device scalars): launch with tile slack,
    // excess blocks exit on the in-kernel ntiles guard.
    const int grid = (HW + TSX * TSY - 1) / (TSX * TSY) + 64;
    warp_pipe5<<<grid, NTHREADS, 0, stream>>>(img, flow, Hp, Wp, out, HW, C);
}

// Round 19
// 128.526 us; speedup vs baseline: 1.1332x; 1.1332x over previous
//
#include <hip/hip_runtime.h>

// Bilinear backward warp, NCHW f32 — pipelined LDS channel loop, slimmed.
// Block = 64x32 tile, 1024 threads. LDS: 2 ping-pong buffers x 2 planes of
// (72x40) RAD=4 halo'd tile (46 KB total). Per phase: issue next-phase DMA
// (global_load_lds x2/thread, descriptors precomputed ONCE), gather current
// buffer, then counted s_waitcnt vmcnt(4) + raw s_barrier (output stores stay
// in flight; the 2 oldest VM ops = our DMAs are retired by in-order vmcnt).
//
// Staging slot map is lane-consecutive per wave with no wrap (R10 lesson:
// global_load_lds writes wave-uniform base + lane*16). s=0 -> slot tid
// (0..1023), s=1 -> slot 416+tid (416..1439). All 1440 slots covered;
// 416..1023 staged twice (same src, same dst — benign).
//
// BEST KNOWN: 126.9 us (R11), reproduced 128.4 (R16). Falsified directions:
// depth-2 (R12 131), CGB=3 (R17 146), small-block (R13 145), prod/cons
// (R14 212), per-wave barrier-free (R15 182), direct-gather family (208+).
// Equilibrium: HBM 38%, VALU 14%, LDS ~25%, conflicts 16%, occ 79% —
// the 4-corner NCHW gather redistribution's latency-throughput product.

#define TSX 64
#define TSY 32
#define RAD 4
#define LW  (TSX + 2*RAD)     // 72
#define LH  (TSY + 2*RAD)     // 40
#define GPR (LW/4)            // 18 float4 groups per row
#define PLANE (LW*LH)         // 2880 floats = 11520 B
#define NV  (LH*GPR)          // 720 groups per plane
#define CGB 2                 // channels per buffer
#define NSTG (CGB*NV)         // 1440 DMA slots per phase
#define NTHREADS 1024
#define SOFF (NSTG - NTHREADS)  // 416: second-slot offset

static_assert(NSTG >= NTHREADS && NSTG <= 2*NTHREADS, "2 slots per thread");

#define GLOAD_LDS16(g, l)                                                  \
    __builtin_amdgcn_global_load_lds(                                      \
        (const __attribute__((address_space(1))) void*)(g),                \
        (__attribute__((address_space(3))) void*)(l), 16, 0, 0)

__global__ __launch_bounds__(NTHREADS, 8) void warp_pipe3(
    const float* __restrict__ img,
    const float* __restrict__ flow,
    const int* __restrict__ Hp,
    const int* __restrict__ Wp,
    float* __restrict__ out,
    int HW, int C)
{
    __shared__ __align__(16) float lds[2 * CGB * PLANE];   // 46080 B

    const int W = *Wp;
    const int H = *Hp;
    const int tilesX = (W + TSX - 1) / TSX;
    const int tilesY = (H + TSY - 1) / TSY;
    const int ntiles = tilesX * tilesY;
    const int bid = blockIdx.x;
    if (bid >= ntiles) return;

    // bijective XCD band swizzle
    const int q = ntiles >> 3, r = ntiles & 7;
    const int xcd = bid & 7, sub = bid >> 3;
    const int t = (xcd < r ? xcd*(q+1) : r*(q+1) + (xcd-r)*q) + sub;

    const int tileY = t / tilesX;
    const int tileX = t - tileY * tilesX;
    const int gx0 = tileX * TSX - RAD;   // always ≡ 0 (mod 4)
    const int gy0 = tileY * TSY - RAD;

    const int tid = threadIdx.x;
    const int lx  = tid & 63;
    const int rw  = (tid >> 6) * 2;      // 2 rows per thread
    const int gx  = tileX * TSX + lx;

    const float Wm1 = (float)(W - 1);
    const float Hm1 = (float)(H - 1);

    // ---- per-pixel precompute (once per tile) ----
    float wtl[2], wth[2], wbl[2], wbh[2];
    int enc[2], pixk[2] = {0, 0};
    #pragma unroll
    for (int k = 0; k < 2; ++k) {
        const int gy = tileY * TSY + rw + k;
        enc[k] = -2;
        if (gx >= W || gy >= H) continue;
        const int pix = gy * W + gx;
        pixk[k] = pix;
        const float u = flow[pix];
        const float v = flow[HW + pix];

        // normalize/denormalize round-trip omitted (identity, +-1 ulp)
        const float x = (float)gx + u;
        const float y = (float)gy + v;
        const float x0 = floorf(x), x1 = x0 + 1.0f;
        const float y0 = floorf(y), y1 = y0 + 1.0f;

        const int x0c = (int)fminf(fmaxf(x0, 0.0f), Wm1);
        const int x1c = (int)fminf(fmaxf(x1, 0.0f), Wm1);
        const int y0c = (int)fminf(fmaxf(y0, 0.0f), Hm1);
        const int y1c = (int)fminf(fmaxf(y1, 0.0f), Hm1);

        const float wa = (x1 - x) * (y1 - y);
        const float wb = (x1 - x) * (y - y0);
        const float wc = (x - x0) * (y1 - y);
        const float wd = (x - x0) * (y - y0);

        const int pbx = min(x0c, W - 2);
        const int pby = min(y0c, H - 2);

        const float wlt = (x0c == pbx ? wa : 0.f) + (x1c == pbx ? wc : 0.f);
        const float wht = (x0c != pbx ? wa : 0.f) + (x1c != pbx ? wc : 0.f);
        const float wlb = (x0c == pbx ? wb : 0.f) + (x1c == pbx ? wd : 0.f);
        const float whb = (x0c != pbx ? wb : 0.f) + (x1c != pbx ? wd : 0.f);
        const bool t0 = (y0c == pby), t1 = (y1c == pby);
        wtl[k] = (t0 ? wlt : 0.f) + (t1 ? wlb : 0.f);
        wth[k] = (t0 ? wht : 0.f) + (t1 ? whb : 0.f);
        wbl[k] = (t0 ? 0.f : wlt) + (t1 ? 0.f : wlb);
        wbh[k] = (t0 ? 0.f : wht) + (t1 ? 0.f : whb);

        const int lxp = pbx - gx0;
        const int lyb = pby - gy0;
        enc[k] = (lxp >= 0 && lxp <= LW-2 && lyb >= 0 && lyb <= LH-2)
               ? (lyb * LW + lxp) : -1;
    }

    float* optr0 = out + pixk[0];
    float* optr1 = out + pixk[1];

    // ---- staging descriptors, computed once; lane-consecutive slots ----
    int spix[2], chrel[2], dst4[2];
    #pragma unroll
    for (int s = 0; s < 2; ++s) {
        const int idx = tid + s * SOFF;        // s=0: 0..1023, s=1: 416..1439
        const int ch  = idx / NV;
        const int rem = idx - ch * NV;
        const int rr  = rem / GPR;
        const int g   = rem - rr * GPR;
        const int yy  = min(max(gy0 + rr, 0), H - 1);
        const int xs  = min(max(gx0 + 4*g, 0), W - 4);  // group fully in/out
        chrel[s] = ch;
        spix[s]  = yy * W + xs;
        dst4[s]  = idx * 4;
    }

    const int nph = (C + CGB - 1) / CGB;
    const bool fast = ((W & 3) == 0) && ((tileX+1)*TSX <= W)
                   && ((tileY+1)*TSY <= H);

    // gather one phase from `cur`; stores via optr0/optr1
    auto gather2 = [&](const float* cur, int c0) {
        #pragma unroll
        for (int k = 0; k < 2; ++k) {
            const int e = enc[k];
            if (e == -2) continue;
            float* o = (k == 0) ? optr0 : optr1;
            if (__builtin_expect(e >= 0, 1)) {
                const float* b0 = cur + e;
                const float a0 = wtl[k], a1 = wth[k];
                const float a2 = wbl[k], a3 = wbh[k];
                o[0] = a0*b0[0] + a1*b0[1] + a2*b0[LW] + a3*b0[LW+1];
                if (c0 + 1 < C)
                    o[HW] = a0*b0[PLANE]   + a1*b0[PLANE+1]
                          + a2*b0[PLANE+LW] + a3*b0[PLANE+LW+1];
            } else {
                // rare out-of-halo flow: recompute + global gather
                const int pix = pixk[k];
                const int gy  = tileY * TSY + rw + k;
                const float u = flow[pix];
                const float v = flow[HW + pix];
                const float x = (float)gx + u;
                const float y = (float)gy + v;
                const float x0 = floorf(x), y0f = floorf(y);
                const int x0c = (int)fminf(fmaxf(x0, 0.f), Wm1);
                const int x1c = (int)fminf(fmaxf(x0 + 1.f, 0.f), Wm1);
                const int y0c = (int)fminf(fmaxf(y0f, 0.f), Hm1);
                const int y1c = (int)fminf(fmaxf(y0f + 1.f, 0.f), Hm1);
                const float wa = (x0 + 1.f - x) * (y0f + 1.f - y);
                const float wb = (x0 + 1.f - x) * (y - y0f);
                const float wc = (x - x0) * (y0f + 1.f - y);
                const float wd = (x - x0) * (y - y0f);
                for (int c = 0; c < CGB && c0 + c < C; ++c) {
                    const float* ic = img + (size_t)(c0 + c) * HW;
                    o[(size_t)c * HW] =
                          wa * ic[(size_t)y0c*W + x0c] + wb * ic[(size_t)y1c*W + x0c]
                        + wc * ic[(size_t)y0c*W + x1c] + wd * ic[(size_t)y1c*W + x1c];
                }
            }
        }
    };

    if (fast) {
        // prologue: stage phase 0 into buffer A
        #pragma unroll
        for (int s = 0; s < 2; ++s) {
            const int chc = min(chrel[s], C - 1);
            GLOAD_LDS16(img + (size_t)chc * HW + spix[s], &lds[dst4[s]]);
        }
        asm volatile("s_waitcnt vmcnt(0)" ::: "memory");
        __builtin_amdgcn_s_barrier();
        __builtin_amdgcn_sched_barrier(0);

        float* cur = &lds[0];
        float* nxt = &lds[CGB * PLANE];

        for (int p = 0; p < nph; ++p) {
            const int c0 = p * CGB;

            if (p + 1 < nph) {   // issue DMA for next phase FIRST
                const int c0n = c0 + CGB;
                #pragma unroll
                for (int s = 0; s < 2; ++s) {
                    const int chc = min(c0n + chrel[s], C - 1);
                    GLOAD_LDS16(img + (size_t)chc * HW + spix[s], nxt + dst4[s]);
                }
            }
            __builtin_amdgcn_sched_barrier(0);   // pin: DMAs before stores

            gather2(cur, c0);                    // 4 stores per thread

            __builtin_amdgcn_sched_barrier(0);   // pin: stores before wait

            if (p + 1 < nph) {
                // in-order vmcnt: count<=4 => the 2 oldest (our DMAs) retired;
                // the 4 output stores stay in flight across the barrier.
                asm volatile("s_waitcnt vmcnt(4)" ::: "memory");
                __builtin_amdgcn_sched_barrier(0);
                __builtin_amdgcn_s_barrier();
                __builtin_amdgcn_sched_barrier(0);
            }
            float* tmp = cur; cur = nxt; nxt = tmp;
            optr0 += (size_t)CGB * HW;
            optr1 += (size_t)CGB * HW;
        }
    } else {
        // generic slow path (partial tiles / W%4!=0): scalar stage + full syncs
        for (int p = 0; p < nph; ++p) {
            const int c0 = p * CGB;
            __syncthreads();
            for (int i = tid; i < CGB * PLANE; i += NTHREADS) {
                const int ch  = i / PLANE;
                const int rem = i - ch * PLANE;
                const int rr  = rem / LW;
                const int cc  = rem - rr * LW;
                const int yy  = min(max(gy0 + rr, 0), H - 1);
                const int xx  = min(max(gx0 + cc, 0), W - 1);
                const int chc = min(c0 + ch, C - 1);
                lds[i] = img[(size_t)chc * HW + (size_t)yy * W + xx];
            }
            __syncthreads();
            gather2(&lds[0], c0);
            optr0 += (size_t)CGB * HW;
            optr1 += (size_t)CGB * HW;
        }
    }
}

extern "C" void kernel_launch(void* const* d_in, const int* in_sizes, int n_in,
                              void* d_out, int out_size, void* d_ws, size_t ws_size,
                              hipStream_t stream) {
    const float* img  = (const float*)d_in[0];
    const float* flow = (const float*)d_in[1];
    const int*   Hp   = (const int*)d_in[2];
    const int*   Wp   = (const int*)d_in[3];
    float* out = (float*)d_out;

    const int HW = in_sizes[1] / 2;    // flow is (1,2,H,W)
    const int C  = in_sizes[0] / HW;   // img is (1,C,H,W)

    // host doesn't know W,H (device scalars): launch with tile slack,
    // excess blocks exit on the in-kernel ntiles guard.
    const int grid = (HW + TSX * TSY - 1) / (TSX * TSY) + 64;
    warp_pipe3<<<grid, NTHREADS, 0, stream>>>(img, flow, Hp, Wp, out, HW, C);
}